// Round 1
// baseline (570.812 us; speedup 1.0000x reference)
//
#include <hip/hip_runtime.h>
#include <hip/hip_bf16.h>

// BERTCPCLoss: loss = xe + mse, outputs (loss, xe, mse, acc)
// B=32, S=512, D=1024, DROPNUM=128
//   P (4096,1024) = out_seq gathered at drop_idx ; K (16384,1024) = in_seq flat
//   lossmat = P @ K^T  (4096 x 16384) -> fused row max/argmax/sumexp/target-logit
// Split-bf16 (hi+lo) 3-MFMA GEMM for ~fp32 accuracy at bf16 MFMA rate.

typedef __attribute__((ext_vector_type(8))) short short8;
typedef __attribute__((ext_vector_type(4))) float f32x4;

#define MFMA(a, b, c) __builtin_amdgcn_mfma_f32_16x16x32_bf16((a), (b), (c), 0, 0, 0)

__device__ __forceinline__ void splitbf(float x, unsigned short& h, unsigned short& l) {
    unsigned u = __float_as_uint(x);
    unsigned short hh = (unsigned short)((u + 0x7fffu + ((u >> 16) & 1u)) >> 16);
    float hf = __uint_as_float(((unsigned)hh) << 16);
    float r = x - hf;
    unsigned u2 = __float_as_uint(r);
    unsigned short ll = (unsigned short)((u2 + 0x7fffu + ((u2 >> 16) & 1u)) >> 16);
    h = hh;
    l = ll;
}

__device__ __forceinline__ void glds16(const unsigned short* g, unsigned short* lds) {
    __builtin_amdgcn_global_load_lds(
        (const __attribute__((address_space(1))) unsigned int*)g,
        (__attribute__((address_space(3))) unsigned int*)lds, 16, 0, 0);
}

// ---- conversion kernels: f32 -> (hi,lo) bf16, pre-swizzled k (XOR bits 3..5 with row&7) ----

__global__ void conv_keys_k(const float* __restrict__ src, unsigned short* __restrict__ h,
                            unsigned short* __restrict__ l) {
    unsigned t = blockIdx.x * 256u + threadIdx.x;
    unsigned idx = t * 4u;               // element index into (16384,1024)
    unsigned row = idx >> 10;
    unsigned k = idx & 1023u;
    float4 v = *(const float4*)(src + idx);
    unsigned kd = k ^ ((row & 7u) << 3);
    unsigned d = (row << 10) + kd;
    ushort4 hv, lv;
    splitbf(v.x, hv.x, lv.x);
    splitbf(v.y, hv.y, lv.y);
    splitbf(v.z, hv.z, lv.z);
    splitbf(v.w, hv.w, lv.w);
    *(ushort4*)(h + d) = hv;
    *(ushort4*)(l + d) = lv;
}

__global__ void conv_preds_k(const float* __restrict__ outseq, const int* __restrict__ drop,
                             unsigned short* __restrict__ h, unsigned short* __restrict__ l,
                             int* __restrict__ tgt) {
    unsigned t = blockIdx.x * 256u + threadIdx.x;
    unsigned idx = t * 4u;               // element index into (4096,1024)
    unsigned prow = idx >> 10;           // 0..4095
    unsigned k = idx & 1023u;
    unsigned b = prow >> 7, j = prow & 127u;
    int srow = drop[b * 128u + j];       // 0..511
    unsigned gsrc = ((b << 9) + (unsigned)srow) * 1024u + k;
    float4 v = *(const float4*)(outseq + gsrc);
    unsigned kd = k ^ ((prow & 7u) << 3);
    unsigned d = (prow << 10) + kd;
    ushort4 hv, lv;
    splitbf(v.x, hv.x, lv.x);
    splitbf(v.y, hv.y, lv.y);
    splitbf(v.z, hv.z, lv.z);
    splitbf(v.w, hv.w, lv.w);
    *(ushort4*)(h + d) = hv;
    *(ushort4*)(l + d) = lv;
    if (k == 0) tgt[prow] = (int)((b << 9) + (unsigned)srow);
}

// ---- fused GEMM + per-(row,chunk) online-softmax partials ----
// grid (128 n-tiles, 32 m-tiles), 256 threads (4 waves, 2x2), 64 KiB dyn LDS.

__global__ __launch_bounds__(256, 2) void gemm_stats_k(
    const unsigned short* __restrict__ Ph, const unsigned short* __restrict__ Pl,
    const unsigned short* __restrict__ Kh, const unsigned short* __restrict__ Kl,
    const int* __restrict__ tgt,
    float* __restrict__ pmax, float* __restrict__ psum, int* __restrict__ pidx,
    float* __restrict__ xt) {
    extern __shared__ unsigned short lds[];  // [4][128][64] : Ah, Al, Bh, Bl

    const int tid = threadIdx.x;
    const int lane = tid & 63;
    const int wave = tid >> 6;
    const int wm = wave >> 1, wn = wave & 1;
    const int bm = blockIdx.y, bn = blockIdx.x;
    const int lr = lane & 15, lk = lane >> 4;

    // staging geometry: granule g = is*256+tid ; row = g>>3, gcol = g&7 (16B granules)
    const int srow = tid >> 3;  // 0..31 (+32 per issue)
    const int sgc = tid & 7;

    const size_t aRow0 = (size_t)(bm * 128 + srow) * 1024 + sgc * 8;
    const size_t bRow0 = (size_t)(bn * 128 + srow) * 1024 + sgc * 8;
    const unsigned short* gAh = Ph + aRow0;
    const unsigned short* gAl = Pl + aRow0;
    const unsigned short* gBh = Kh + bRow0;
    const unsigned short* gBl = Kl + bRow0;

    f32x4 acc[4][4] = {};

    for (int kt = 0; kt < 16; ++kt) {
        const unsigned kof = kt * 64u;
#pragma unroll
        for (int is = 0; is < 4; ++is) {
            unsigned lo = (is * 256 + tid) * 8;  // lds element offset
            size_t go = (size_t)is * 32 * 1024 + kof;
            glds16(gAh + go, &lds[lo]);
            glds16(gAl + go, &lds[8192 + lo]);
            glds16(gBh + go, &lds[16384 + lo]);
            glds16(gBl + go, &lds[24576 + lo]);
        }
        __syncthreads();

#pragma unroll
        for (int ks = 0; ks < 2; ++ks) {
            short8 ah[4], al[4], bh[4], bl[4];
#pragma unroll
            for (int i = 0; i < 4; ++i) {
                int r = wm * 64 + i * 16 + lr;
                int kl = (ks * 32 + lk * 8) ^ ((r & 7) << 3);
                int off = r * 64 + kl;
                ah[i] = *(const short8*)&lds[off];
                al[i] = *(const short8*)&lds[8192 + off];
            }
#pragma unroll
            for (int n = 0; n < 4; ++n) {
                int r = wn * 64 + n * 16 + lr;
                int kl = (ks * 32 + lk * 8) ^ ((r & 7) << 3);
                int off = r * 64 + kl;
                bh[n] = *(const short8*)&lds[16384 + off];
                bl[n] = *(const short8*)&lds[24576 + off];
            }
#pragma unroll
            for (int i = 0; i < 4; ++i)
#pragma unroll
                for (int n = 0; n < 4; ++n) {
                    acc[i][n] = MFMA(ah[i], bh[n], acc[i][n]);
                    acc[i][n] = MFMA(ah[i], bl[n], acc[i][n]);
                    acc[i][n] = MFMA(al[i], bh[n], acc[i][n]);
                }
        }
        __syncthreads();
    }

    // epilogue: per-row (64-col chunk) max / argmax / sumexp / target logit
    const int chunk = bn * 2 + wn;  // 0..255
#pragma unroll
    for (int i = 0; i < 4; ++i) {
#pragma unroll
        for (int j = 0; j < 4; ++j) {
            int grow = bm * 128 + wm * 64 + i * 16 + lk * 4 + j;
            int tcol = tgt[grow];
            float v[4];
            float mx = -3.0e38f;
            int am = 0;
#pragma unroll
            for (int n = 0; n < 4; ++n) {
                v[n] = acc[i][n][j];
                int gcol = bn * 128 + wn * 64 + n * 16 + lr;
                if (gcol == tcol) xt[grow] = v[n];
                if (v[n] > mx) { mx = v[n]; am = gcol; }
            }
            float s = 0.f;
#pragma unroll
            for (int n = 0; n < 4; ++n) s += expf(v[n] - mx);
            // reduce across the 16 lanes (lr dimension)
#pragma unroll
            for (int off = 1; off < 16; off <<= 1) {
                float om = __shfl_xor(mx, off);
                float os = __shfl_xor(s, off);
                int oa = __shfl_xor(am, off);
                float M = fmaxf(mx, om);
                s = s * expf(mx - M) + os * expf(om - M);
                am = (om > mx || (om == mx && oa < am)) ? oa : am;
                mx = M;
            }
            if (lr == 0) {
                pmax[grow * 256 + chunk] = mx;
                psum[grow * 256 + chunk] = s;
                pidx[grow * 256 + chunk] = am;
            }
        }
    }
}

// ---- combine 256 chunks per row -> row xe / hit ----
__global__ void pass2_k(const float* __restrict__ pmax, const float* __restrict__ psum,
                        const int* __restrict__ pidx, const float* __restrict__ xt,
                        const int* __restrict__ tgt, float* __restrict__ rxe,
                        float* __restrict__ rhit) {
    int row = blockIdx.x;
    int t = threadIdx.x;  // 64 threads
    float m = -3.0e38f, l = 0.f;
    int ai = 0x7fffffff;
    for (int c = t; c < 256; c += 64) {
        float cm = pmax[row * 256 + c];
        float cl = psum[row * 256 + c];
        int ci = pidx[row * 256 + c];
        if (cm > m || (cm == m && ci < ai)) {
            l = l * expf(m - cm) + cl;
            ai = ci;
            m = cm;
        } else {
            l += cl * expf(cm - m);
        }
    }
#pragma unroll
    for (int off = 1; off < 64; off <<= 1) {
        float om = __shfl_xor(m, off);
        float ol = __shfl_xor(l, off);
        int oi = __shfl_xor(ai, off);
        if (om > m || (om == m && oi < ai)) {
            l = l * expf(m - om) + ol;
            ai = oi;
            m = om;
        } else {
            l += ol * expf(om - m);
        }
    }
    if (t == 0) {
        rxe[row] = m + logf(l) - xt[row];
        rhit[row] = (ai == tgt[row]) ? 1.f : 0.f;
    }
}

// ---- MSE partials: sum over (b, keep_idx) rows of (in - out)^2 ----
__global__ void mse_partial_k(const float* __restrict__ inseq, const float* __restrict__ outseq,
                              const int* __restrict__ keep, float* __restrict__ msep) {
    float s = 0.f;
    for (unsigned f = blockIdx.x * 256u + threadIdx.x; f < 3145728u; f += 1024u * 256u) {
        unsigned rowid = f >> 8;       // 0..12287
        unsigned kf = (f & 255u) << 2; // element k
        unsigned b = rowid / 384u;
        unsigned j = rowid - b * 384u;
        int r = keep[b * 384u + j];
        size_t base = (((size_t)(b * 512u + (unsigned)r)) << 10) + kf;
        float4 a = *(const float4*)(inseq + base);
        float4 c = *(const float4*)(outseq + base);
        float dx = a.x - c.x, dy = a.y - c.y, dz = a.z - c.z, dw = a.w - c.w;
        s += dx * dx + dy * dy + dz * dz + dw * dw;
    }
#pragma unroll
    for (int off = 1; off < 64; off <<= 1) s += __shfl_xor(s, off);
    __shared__ float red[4];
    if ((threadIdx.x & 63) == 0) red[threadIdx.x >> 6] = s;
    __syncthreads();
    if (threadIdx.x == 0) msep[blockIdx.x] = red[0] + red[1] + red[2] + red[3];
}

// ---- final reduce + outputs ----
__global__ void finalize_k(const float* __restrict__ rxe, const float* __restrict__ rhit,
                           const float* __restrict__ msep, float* __restrict__ out) {
    int tid = threadIdx.x;
    float sx = 0.f, sh = 0.f, sm = 0.f;
    for (int i = tid; i < 4096; i += 256) {
        sx += rxe[i];
        sh += rhit[i];
    }
    for (int i = tid; i < 1024; i += 256) sm += msep[i];
#pragma unroll
    for (int off = 1; off < 64; off <<= 1) {
        sx += __shfl_xor(sx, off);
        sh += __shfl_xor(sh, off);
        sm += __shfl_xor(sm, off);
    }
    __shared__ float red[3][4];
    int w = tid >> 6;
    if ((tid & 63) == 0) {
        red[0][w] = sx;
        red[1][w] = sh;
        red[2][w] = sm;
    }
    __syncthreads();
    if (tid == 0) {
        sx = red[0][0] + red[0][1] + red[0][2] + red[0][3];
        sh = red[1][0] + red[1][1] + red[1][2] + red[1][3];
        sm = red[2][0] + red[2][1] + red[2][2] + red[2][3];
        float xe = sx * (1.f / 4096.f);
        float mse = sm / (12288.f * 1024.f);
        float accp = 100.f * sh * (1.f / 4096.f);
        out[0] = xe + mse;
        out[1] = xe;
        out[2] = mse;
        out[3] = accp;
    }
}

extern "C" void kernel_launch(void* const* d_in, const int* in_sizes, int n_in,
                              void* d_out, int out_size, void* d_ws, size_t ws_size,
                              hipStream_t stream) {
    const float* in_seq = (const float*)d_in[0];
    const float* out_seq = (const float*)d_in[1];
    const int* drop = (const int*)d_in[2];
    const int* keep = (const int*)d_in[3];
    float* out = (float*)d_out;

    char* w = (char*)d_ws;
    unsigned short* Kh = (unsigned short*)w; w += 33554432;  // 16384*1024*2
    unsigned short* Kl = (unsigned short*)w; w += 33554432;
    unsigned short* Ph = (unsigned short*)w; w += 8388608;   // 4096*1024*2
    unsigned short* Pl = (unsigned short*)w; w += 8388608;
    float* pmax = (float*)w; w += 4194304;                   // 4096*256*4
    float* psum = (float*)w; w += 4194304;
    int* pidx = (int*)w; w += 4194304;
    float* xt = (float*)w; w += 16384;
    int* tgt = (int*)w; w += 16384;
    float* rxe = (float*)w; w += 16384;
    float* rhit = (float*)w; w += 16384;
    float* msep = (float*)w; w += 4096;

    conv_keys_k<<<16384, 256, 0, stream>>>(in_seq, Kh, Kl);
    conv_preds_k<<<4096, 256, 0, stream>>>(out_seq, drop, Ph, Pl, tgt);
    gemm_stats_k<<<dim3(128, 32), 256, 65536, stream>>>(Ph, Pl, Kh, Kl, tgt, pmax, psum, pidx, xt);
    pass2_k<<<4096, 64, 0, stream>>>(pmax, psum, pidx, xt, tgt, rxe, rhit);
    mse_partial_k<<<1024, 256, 0, stream>>>(in_seq, out_seq, keep, msep);
    finalize_k<<<1, 256, 0, stream>>>(rxe, rhit, msep, out);
}

// Round 2
// 402.980 us; speedup vs baseline: 1.4165x; 1.4165x over previous
//
#include <hip/hip_runtime.h>
#include <hip/hip_bf16.h>

// BERTCPCLoss: outputs (loss, xe, mse, acc). B=32, S=512, D=1024, DROPNUM=128
//   P (4096,1024) = out_seq gathered at drop_idx ; K (16384,1024) = in_seq flat
//   lossmat = P @ K^T (4096 x 16384) fused with row max/argmax/sumexp/target-logit.
// fp16 single-MFMA GEMM (error sigma ~0.01 on logits of sigma ~32 -> ~100x margin
// vs the 2.58 output threshold), 128x128 tile, BK=64, double-buffered LDS with
// prefetch-before-compute (T3 minimum 2-phase), pre-swizzled K for conflict-free
// ds_read_b128 with linear global_load_lds (rule #21: swizzle source + read).

typedef __attribute__((ext_vector_type(8))) _Float16 half8;
typedef __attribute__((ext_vector_type(4))) _Float16 half4v;
typedef __attribute__((ext_vector_type(4))) float f32x4;

#define MFMA16(a, b, c) __builtin_amdgcn_mfma_f32_16x16x32_f16((a), (b), (c), 0, 0, 0)

__device__ __forceinline__ void glds16(const _Float16* g, _Float16* l) {
    __builtin_amdgcn_global_load_lds(
        (const __attribute__((address_space(1))) unsigned int*)g,
        (__attribute__((address_space(3))) unsigned int*)l, 16, 0, 0);
}

// ---- fused conversion: f32 -> fp16, pre-swizzled k (XOR bits 3..5 with row&7) ----
// blocks [0,16384): keys (in_seq -> Kf) ; blocks [16384,20480): preds (out_seq gathered -> Pf)
__global__ void conv_k(const float* __restrict__ in_seq, const float* __restrict__ out_seq,
                       const int* __restrict__ drop, _Float16* __restrict__ Kf,
                       _Float16* __restrict__ Pf, int* __restrict__ tgt) {
    unsigned bid = blockIdx.x;
    if (bid < 16384u) {
        unsigned t = bid * 256u + threadIdx.x;
        unsigned idx = t * 4u;               // element index into (16384,1024)
        unsigned row = idx >> 10;
        unsigned k = idx & 1023u;
        float4 v = *(const float4*)(in_seq + idx);
        unsigned d = (row << 10) + (k ^ ((row & 7u) << 3));
        half4v o = {(_Float16)v.x, (_Float16)v.y, (_Float16)v.z, (_Float16)v.w};
        *(half4v*)(Kf + d) = o;
    } else {
        unsigned t = (bid - 16384u) * 256u + threadIdx.x;
        unsigned idx = t * 4u;               // element index into (4096,1024)
        unsigned prow = idx >> 10;           // 0..4095
        unsigned k = idx & 1023u;
        unsigned b = prow >> 7, j = prow & 127u;
        int srow = drop[b * 128u + j];       // 0..511
        size_t gsrc = ((size_t)((b << 9) + (unsigned)srow) << 10) + k;
        float4 v = *(const float4*)(out_seq + gsrc);
        unsigned d = (prow << 10) + (k ^ ((prow & 7u) << 3));
        half4v o = {(_Float16)v.x, (_Float16)v.y, (_Float16)v.z, (_Float16)v.w};
        *(half4v*)(Pf + d) = o;
        if (k == 0) tgt[prow] = (int)((b << 9) + (unsigned)srow);
    }
}

// ---- fused GEMM + per-(row,chunk) online-softmax partials ----
// grid (128 n-tiles, 32 m-tiles), 256 threads (4 waves, 2x2), 64 KiB dyn LDS
// (2 buffers x [A 128x64 | B 128x64] fp16), prefetch tile k+1 before compute of k.
__global__ __launch_bounds__(256, 2) void gemm_stats_k(
    const _Float16* __restrict__ Pf, const _Float16* __restrict__ Kf,
    const int* __restrict__ tgt,
    float* __restrict__ pmax, float* __restrict__ psum, int* __restrict__ pidx,
    float* __restrict__ xt) {
    extern __shared__ _Float16 lds[];  // [2][2][128][64] : buf{0,1} x {A,B}

    const int tid = threadIdx.x;
    const int lane = tid & 63;
    const int wave = tid >> 6;
    const int wm = wave >> 1, wn = wave & 1;
    const int bm = blockIdx.y, bn = blockIdx.x;
    const int lr = lane & 15, lk = lane >> 4;

    // staging geometry: 16B granules; per issue 256 threads cover 32 rows x 64 cols
    const int srow = tid >> 3;  // 0..31
    const int sgc = tid & 7;

    const _Float16* gA = Pf + (size_t)(bm * 128 + srow) * 1024 + sgc * 8;
    const _Float16* gB = Kf + (size_t)(bn * 128 + srow) * 1024 + sgc * 8;

    f32x4 acc[4][4] = {};

    auto STAGE = [&](int buf, int kt) {
        const unsigned base = buf * 16384;
        const unsigned kof = kt * 64u;
#pragma unroll
        for (int is = 0; is < 4; ++is) {
            unsigned lo = base + (is * 256 + tid) * 8;
            size_t go = (size_t)is * 32 * 1024 + kof;
            glds16(gA + go, &lds[lo]);
            glds16(gB + go, &lds[8192 + lo]);
        }
    };

    auto COMPUTE = [&](int buf) {
        const unsigned base = buf * 16384;
#pragma unroll
        for (int ks = 0; ks < 2; ++ks) {
            half8 a[4], b[4];
#pragma unroll
            for (int i = 0; i < 4; ++i) {
                int r = wm * 64 + i * 16 + lr;
                int kl = (ks * 32 + lk * 8) ^ ((r & 7) << 3);
                a[i] = *(const half8*)&lds[base + r * 64 + kl];
            }
#pragma unroll
            for (int n = 0; n < 4; ++n) {
                int r = wn * 64 + n * 16 + lr;
                int kl = (ks * 32 + lk * 8) ^ ((r & 7) << 3);
                b[n] = *(const half8*)&lds[base + 8192 + r * 64 + kl];
            }
#pragma unroll
            for (int i = 0; i < 4; ++i)
#pragma unroll
                for (int n = 0; n < 4; ++n) acc[i][n] = MFMA16(a[i], b[n], acc[i][n]);
        }
    };

    STAGE(0, 0);
    __syncthreads();  // drain prologue loads
    int cur = 0;
    for (int kt = 0; kt < 16; ++kt) {
        if (kt < 15) STAGE(cur ^ 1, kt + 1);  // issue next-tile loads (overlap w/ MFMA)
        COMPUTE(cur);
        __syncthreads();  // drains vmcnt(0): next tile landed; lgkm done
        cur ^= 1;
    }

    // epilogue: per-row (64-col chunk) max / argmax / sumexp / target logit
    const int chunk = bn * 2 + wn;  // 0..255
#pragma unroll
    for (int i = 0; i < 4; ++i) {
#pragma unroll
        for (int j = 0; j < 4; ++j) {
            int grow = bm * 128 + wm * 64 + i * 16 + lk * 4 + j;
            int tcol = tgt[grow];
            float v[4];
            float mx = -3.0e38f;
            int am = 0;
#pragma unroll
            for (int n = 0; n < 4; ++n) {
                v[n] = acc[i][n][j];
                int gcol = bn * 128 + wn * 64 + n * 16 + lr;
                if (gcol == tcol) xt[grow] = v[n];
                if (v[n] > mx) { mx = v[n]; am = gcol; }
            }
            float s = 0.f;
#pragma unroll
            for (int n = 0; n < 4; ++n) s += expf(v[n] - mx);
            // reduce across the 16 lanes (lr dimension)
#pragma unroll
            for (int off = 1; off < 16; off <<= 1) {
                float om = __shfl_xor(mx, off);
                float os = __shfl_xor(s, off);
                int oa = __shfl_xor(am, off);
                float M = fmaxf(mx, om);
                s = s * expf(mx - M) + os * expf(om - M);
                am = (om > mx || (om == mx && oa < am)) ? oa : am;
                mx = M;
            }
            if (lr == 0) {
                pmax[grow * 256 + chunk] = mx;
                psum[grow * 256 + chunk] = s;
                pidx[grow * 256 + chunk] = am;
            }
        }
    }
}

// ---- combine 256 chunks per row -> row xe / hit ----
__global__ void pass2_k(const float* __restrict__ pmax, const float* __restrict__ psum,
                        const int* __restrict__ pidx, const float* __restrict__ xt,
                        const int* __restrict__ tgt, float* __restrict__ rxe,
                        float* __restrict__ rhit) {
    int row = blockIdx.x;
    int t = threadIdx.x;  // 64 threads
    float m = -3.0e38f, l = 0.f;
    int ai = 0x7fffffff;
    for (int c = t; c < 256; c += 64) {
        float cm = pmax[row * 256 + c];
        float cl = psum[row * 256 + c];
        int ci = pidx[row * 256 + c];
        if (cm > m || (cm == m && ci < ai)) {
            l = l * expf(m - cm) + cl;
            ai = ci;
            m = cm;
        } else {
            l += cl * expf(cm - m);
        }
    }
#pragma unroll
    for (int off = 1; off < 64; off <<= 1) {
        float om = __shfl_xor(m, off);
        float ol = __shfl_xor(l, off);
        int oi = __shfl_xor(ai, off);
        if (om > m || (om == m && oi < ai)) {
            l = l * expf(m - om) + ol;
            ai = oi;
            m = om;
        } else {
            l += ol * expf(om - m);
        }
    }
    if (t == 0) {
        rxe[row] = m + logf(l) - xt[row];
        rhit[row] = (ai == tgt[row]) ? 1.f : 0.f;
    }
}

// ---- MSE partials: sum over (b, keep_idx) rows of (in - out)^2 ----
__global__ void mse_partial_k(const float* __restrict__ inseq, const float* __restrict__ outseq,
                              const int* __restrict__ keep, float* __restrict__ msep) {
    float s = 0.f;
    for (unsigned f = blockIdx.x * 256u + threadIdx.x; f < 3145728u; f += 1024u * 256u) {
        unsigned rowid = f >> 8;       // 0..12287
        unsigned kf = (f & 255u) << 2; // element k
        unsigned b = rowid / 384u;
        unsigned j = rowid - b * 384u;
        int r = keep[b * 384u + j];
        size_t base = (((size_t)(b * 512u + (unsigned)r)) << 10) + kf;
        float4 a = *(const float4*)(inseq + base);
        float4 c = *(const float4*)(outseq + base);
        float dx = a.x - c.x, dy = a.y - c.y, dz = a.z - c.z, dw = a.w - c.w;
        s += dx * dx + dy * dy + dz * dz + dw * dw;
    }
#pragma unroll
    for (int off = 1; off < 64; off <<= 1) s += __shfl_xor(s, off);
    __shared__ float red[4];
    if ((threadIdx.x & 63) == 0) red[threadIdx.x >> 6] = s;
    __syncthreads();
    if (threadIdx.x == 0) msep[blockIdx.x] = red[0] + red[1] + red[2] + red[3];
}

// ---- final reduce + outputs ----
__global__ void finalize_k(const float* __restrict__ rxe, const float* __restrict__ rhit,
                           const float* __restrict__ msep, float* __restrict__ out) {
    int tid = threadIdx.x;
    float sx = 0.f, sh = 0.f, sm = 0.f;
    for (int i = tid; i < 4096; i += 256) {
        sx += rxe[i];
        sh += rhit[i];
    }
    for (int i = tid; i < 1024; i += 256) sm += msep[i];
#pragma unroll
    for (int off = 1; off < 64; off <<= 1) {
        sx += __shfl_xor(sx, off);
        sh += __shfl_xor(sh, off);
        sm += __shfl_xor(sm, off);
    }
    __shared__ float red[3][4];
    int w = tid >> 6;
    if ((tid & 63) == 0) {
        red[0][w] = sx;
        red[1][w] = sh;
        red[2][w] = sm;
    }
    __syncthreads();
    if (tid == 0) {
        sx = red[0][0] + red[0][1] + red[0][2] + red[0][3];
        sh = red[1][0] + red[1][1] + red[1][2] + red[1][3];
        sm = red[2][0] + red[2][1] + red[2][2] + red[2][3];
        float xe = sx * (1.f / 4096.f);
        float mse = sm / (12288.f * 1024.f);
        float accp = 100.f * sh * (1.f / 4096.f);
        out[0] = xe + mse;
        out[1] = xe;
        out[2] = mse;
        out[3] = accp;
    }
}

extern "C" void kernel_launch(void* const* d_in, const int* in_sizes, int n_in,
                              void* d_out, int out_size, void* d_ws, size_t ws_size,
                              hipStream_t stream) {
    const float* in_seq = (const float*)d_in[0];
    const float* out_seq = (const float*)d_in[1];
    const int* drop = (const int*)d_in[2];
    const int* keep = (const int*)d_in[3];
    float* out = (float*)d_out;

    char* w = (char*)d_ws;
    _Float16* Kf = (_Float16*)w; w += 33554432;  // 16384*1024*2
    _Float16* Pf = (_Float16*)w; w += 8388608;   // 4096*1024*2
    float* pmax = (float*)w; w += 4194304;       // 4096*256*4
    float* psum = (float*)w; w += 4194304;
    int* pidx = (int*)w; w += 4194304;
    float* xt = (float*)w; w += 16384;
    int* tgt = (int*)w; w += 16384;
    float* rxe = (float*)w; w += 16384;
    float* rhit = (float*)w; w += 16384;
    float* msep = (float*)w; w += 4096;

    conv_k<<<20480, 256, 0, stream>>>(in_seq, out_seq, drop, Kf, Pf, tgt);
    gemm_stats_k<<<dim3(128, 32), 256, 65536, stream>>>(Pf, Kf, tgt, pmax, psum, pidx, xt);
    pass2_k<<<4096, 64, 0, stream>>>(pmax, psum, pidx, xt, tgt, rxe, rhit);
    mse_partial_k<<<1024, 256, 0, stream>>>(in_seq, out_seq, keep, msep);
    finalize_k<<<1, 256, 0, stream>>>(rxe, rhit, msep, out);
}

// Round 3
// 379.065 us; speedup vs baseline: 1.5058x; 1.0631x over previous
//
#include <hip/hip_runtime.h>
#include <hip/hip_bf16.h>

// BERTCPCLoss: outputs (loss, xe, mse, acc). B=32, S=512, D=1024, DROPNUM=128
// lossmat = P @ K^T (4096 x 16384), P pre-scaled by log2(e) so softmax runs in
// exp2 domain (v_exp_f32 directly). GEMM: fp16 MFMA 16x16x32, BM=128 BN=256
// BK=64, 8 waves (2x4, 64x64 per wave), 3-buffer LDS ring (144 KiB) with
// counted s_waitcnt vmcnt(6) (T4) + raw s_barrier + sched_barrier fences,
// XCD-swizzled blockIdx (T1), setprio around MFMA (T5). K pre-swizzled in
// global (XOR k bits 3-5 with row&7) so global_load_lds stays linear and
// ds_read_b128 applies the XOR -> 0 bank conflicts (verified rounds 1-2).

typedef __attribute__((ext_vector_type(8))) _Float16 half8;
typedef __attribute__((ext_vector_type(4))) _Float16 half4v;
typedef __attribute__((ext_vector_type(4))) float f32x4;

#define MFMA16(a, b, c) __builtin_amdgcn_mfma_f32_16x16x32_f16((a), (b), (c), 0, 0, 0)

__device__ __forceinline__ float fexp2(float x) {
    float r;
    asm("v_exp_f32 %0, %1" : "=v"(r) : "v"(x));
    return r;
}
__device__ __forceinline__ float flog2(float x) {
    float r;
    asm("v_log_f32 %0, %1" : "=v"(r) : "v"(x));
    return r;
}

__device__ __forceinline__ void glds16(const _Float16* g, _Float16* l) {
    __builtin_amdgcn_global_load_lds(
        (const __attribute__((address_space(1))) unsigned int*)g,
        (__attribute__((address_space(3))) unsigned int*)l, 16, 0, 0);
}

// ---- conversion: f32 -> fp16, pre-swizzled k (XOR bits 3..5 with row&7) ----
// P additionally scaled by log2(e). blocks [0,16384): keys; [16384,20480): preds.
__global__ void conv_k(const float* __restrict__ in_seq, const float* __restrict__ out_seq,
                       const int* __restrict__ drop, _Float16* __restrict__ Kf,
                       _Float16* __restrict__ Pf, int* __restrict__ tgt) {
    const float C = 1.4426950408889634f;
    unsigned bid = blockIdx.x;
    if (bid < 16384u) {
        unsigned t = bid * 256u + threadIdx.x;
        unsigned idx = t * 4u;
        unsigned row = idx >> 10;
        unsigned k = idx & 1023u;
        float4 v = *(const float4*)(in_seq + idx);
        unsigned d = (row << 10) + (k ^ ((row & 7u) << 3));
        half4v o = {(_Float16)v.x, (_Float16)v.y, (_Float16)v.z, (_Float16)v.w};
        *(half4v*)(Kf + d) = o;
    } else {
        unsigned t = (bid - 16384u) * 256u + threadIdx.x;
        unsigned idx = t * 4u;
        unsigned prow = idx >> 10;
        unsigned k = idx & 1023u;
        unsigned b = prow >> 7, j = prow & 127u;
        int srow = drop[b * 128u + j];
        size_t gsrc = ((size_t)((b << 9) + (unsigned)srow) << 10) + k;
        float4 v = *(const float4*)(out_seq + gsrc);
        unsigned d = (prow << 10) + (k ^ ((prow & 7u) << 3));
        half4v o = {(_Float16)(v.x * C), (_Float16)(v.y * C), (_Float16)(v.z * C),
                    (_Float16)(v.w * C)};
        *(half4v*)(Pf + d) = o;
        if (k == 0) tgt[prow] = (int)((b << 9) + (unsigned)srow);
    }
}

// ---- fused GEMM + per-(row,chunk) softmax partials (exp2 domain) ----
#define LDSB 24576  // elems/buffer: A 128x64 (8192) + B 256x64 (16384)

__global__ __launch_bounds__(512, 2) void gemm_stats_k(
    const _Float16* __restrict__ Pf, const _Float16* __restrict__ Kf,
    const int* __restrict__ tgt,
    float* __restrict__ pmax, float* __restrict__ psum, int* __restrict__ pidx,
    float* __restrict__ xt) {
    extern __shared__ _Float16 lds[];  // 3 * LDSB elems = 144 KiB

    const int tid = threadIdx.x;       // 512
    const int lane = tid & 63;
    const int wave = tid >> 6;         // 0..7
    const int wm = wave >> 2, wn = wave & 3;
    const int lr = lane & 15, lk = lane >> 4;

    // XCD-aware bijective swizzle: 2048 blocks, 8 XCDs, 256 per XCD
    unsigned id = blockIdx.x;
    unsigned wg = (id & 7u) * 256u + (id >> 3);
    const int bn = wg & 63, bm = wg >> 6;

    // staging: 16B granules, linear LDS dest (lane x 16B), linear global src
    const int sr = tid >> 3;  // 0..63
    const int sgc = tid & 7;
    const _Float16* gA = Pf + (size_t)(bm * 128 + sr) * 1024 + sgc * 8;
    const _Float16* gB = Kf + (size_t)(bn * 256 + sr) * 1024 + sgc * 8;

    f32x4 acc[4][4] = {};

    auto STAGE = [&](int buf, int kt) {
        const unsigned kof = kt * 64u;
        const unsigned base = buf * LDSB;
#pragma unroll
        for (int is = 0; is < 2; ++is)
            glds16(gA + (size_t)is * 64 * 1024 + kof, &lds[base + (is * 512 + tid) * 8]);
#pragma unroll
        for (int is = 0; is < 4; ++is)
            glds16(gB + (size_t)is * 64 * 1024 + kof, &lds[base + 8192 + (is * 512 + tid) * 8]);
    };

    auto COMPUTE = [&](int buf) {
        const _Float16* La = &lds[buf * LDSB];
        const _Float16* Lb = &lds[buf * LDSB + 8192];
#pragma unroll
        for (int ks = 0; ks < 2; ++ks) {
            half8 a[4], b[4];
#pragma unroll
            for (int i = 0; i < 4; ++i) {
                int r = wm * 64 + i * 16 + lr;
                int kl = (ks * 32 + lk * 8) ^ ((r & 7) << 3);
                a[i] = *(const half8*)&La[r * 64 + kl];
            }
#pragma unroll
            for (int n = 0; n < 4; ++n) {
                int r = wn * 64 + n * 16 + lr;
                int kl = (ks * 32 + lk * 8) ^ ((r & 7) << 3);
                b[n] = *(const half8*)&Lb[r * 64 + kl];
            }
            __builtin_amdgcn_s_setprio(1);
#pragma unroll
            for (int i = 0; i < 4; ++i)
#pragma unroll
                for (int n = 0; n < 4; ++n) acc[i][n] = MFMA16(a[i], b[n], acc[i][n]);
            __builtin_amdgcn_s_setprio(0);
        }
    };

    // prologue: stage tiles 0,1; wait tile 0 (retire oldest 6 of 12); barrier
    STAGE(0, 0);
    STAGE(1, 1);
    asm volatile("s_waitcnt vmcnt(6)" ::: "memory");
    __builtin_amdgcn_s_barrier();
    __builtin_amdgcn_sched_barrier(0);

#pragma unroll
    for (int kt = 0; kt < 16; ++kt) {
        if (kt + 2 < 16) STAGE((kt + 2) % 3, kt + 2);  // writes buf last read at kt-1: safe
        COMPUTE(kt % 3);
        // end-of-iter: guarantee tile kt+1 resident. In flight: tiles kt+1, kt+2 (6 loads each)
        if (kt < 14) {
            asm volatile("s_waitcnt vmcnt(6)" ::: "memory");
        } else if (kt == 14) {
            asm volatile("s_waitcnt vmcnt(0)" ::: "memory");
        }
        if (kt < 15) {
            __builtin_amdgcn_s_barrier();
            __builtin_amdgcn_sched_barrier(0);
        }
    }

    // epilogue: per-row 64-col chunk stats; all in exp2 domain
    const int chunk = bn * 4 + wn;  // 0..255
#pragma unroll
    for (int i = 0; i < 4; ++i) {
#pragma unroll
        for (int j = 0; j < 4; ++j) {
            int grow = bm * 128 + wm * 64 + i * 16 + lk * 4 + j;
            int tcol = tgt[grow];
            float v0 = acc[i][0][j], v1 = acc[i][1][j], v2 = acc[i][2][j], v3 = acc[i][3][j];
            int c0 = bn * 256 + wn * 64 + lr;
            if (c0 == tcol) xt[grow] = v0;
            if (c0 + 16 == tcol) xt[grow] = v1;
            if (c0 + 32 == tcol) xt[grow] = v2;
            if (c0 + 48 == tcol) xt[grow] = v3;
            float mx = fmaxf(fmaxf(v0, v1), fmaxf(v2, v3));
#pragma unroll
            for (int off = 1; off < 16; off <<= 1) mx = fmaxf(mx, __shfl_xor(mx, off));
            // first-occurrence argmax: min col among elements equal to chunk max
            int am = v0 == mx ? c0
                   : v1 == mx ? c0 + 16
                   : v2 == mx ? c0 + 32
                   : v3 == mx ? c0 + 48
                              : 0x7fffffff;
#pragma unroll
            for (int off = 1; off < 16; off <<= 1) {
                int o = __shfl_xor(am, off);
                am = o < am ? o : am;
            }
            float s = fexp2(v0 - mx) + fexp2(v1 - mx) + fexp2(v2 - mx) + fexp2(v3 - mx);
#pragma unroll
            for (int off = 1; off < 16; off <<= 1) s += __shfl_xor(s, off);
            if (lr == 0) {
                pmax[grow * 256 + chunk] = mx;
                psum[grow * 256 + chunk] = s;
                pidx[grow * 256 + chunk] = am;
            }
        }
    }
}

// ---- combine 256 chunks per row -> row xe / hit (exp2 domain) ----
__global__ void pass2_k(const float* __restrict__ pmax, const float* __restrict__ psum,
                        const int* __restrict__ pidx, const float* __restrict__ xt,
                        const int* __restrict__ tgt, float* __restrict__ rxe,
                        float* __restrict__ rhit) {
    int row = blockIdx.x;
    int t = threadIdx.x;  // 64
    float m = -3.0e38f, l = 0.f;
    int ai = 0x7fffffff;
    for (int c = t; c < 256; c += 64) {
        float cm = pmax[row * 256 + c];
        float cl = psum[row * 256 + c];
        int ci = pidx[row * 256 + c];
        if (cm > m || (cm == m && ci < ai)) {
            l = l * fexp2(m - cm) + cl;
            ai = ci;
            m = cm;
        } else {
            l += cl * fexp2(cm - m);
        }
    }
#pragma unroll
    for (int off = 1; off < 64; off <<= 1) {
        float om = __shfl_xor(m, off);
        float ol = __shfl_xor(l, off);
        int oi = __shfl_xor(ai, off);
        if (om > m || (om == m && oi < ai)) {
            l = l * fexp2(m - om) + ol;
            ai = oi;
            m = om;
        } else {
            l += ol * fexp2(om - m);
        }
    }
    if (t == 0) {
        // logits were scaled by log2(e): xe_row = (m + log2(l) - xt) * ln(2)
        rxe[row] = (m + flog2(l) - xt[row]) * 0.69314718055994531f;
        rhit[row] = (ai == tgt[row]) ? 1.f : 0.f;
    }
}

// ---- MSE partials ----
__global__ void mse_partial_k(const float* __restrict__ inseq, const float* __restrict__ outseq,
                              const int* __restrict__ keep, float* __restrict__ msep) {
    float s = 0.f;
    for (unsigned f = blockIdx.x * 256u + threadIdx.x; f < 3145728u; f += 1024u * 256u) {
        unsigned rowid = f >> 8;
        unsigned kf = (f & 255u) << 2;
        unsigned b = rowid / 384u;
        unsigned j = rowid - b * 384u;
        int r = keep[b * 384u + j];
        size_t base = (((size_t)(b * 512u + (unsigned)r)) << 10) + kf;
        float4 a = *(const float4*)(inseq + base);
        float4 c = *(const float4*)(outseq + base);
        float dx = a.x - c.x, dy = a.y - c.y, dz = a.z - c.z, dw = a.w - c.w;
        s += dx * dx + dy * dy + dz * dz + dw * dw;
    }
#pragma unroll
    for (int off = 1; off < 64; off <<= 1) s += __shfl_xor(s, off);
    __shared__ float red[4];
    if ((threadIdx.x & 63) == 0) red[threadIdx.x >> 6] = s;
    __syncthreads();
    if (threadIdx.x == 0) msep[blockIdx.x] = red[0] + red[1] + red[2] + red[3];
}

// ---- final reduce ----
__global__ void finalize_k(const float* __restrict__ rxe, const float* __restrict__ rhit,
                           const float* __restrict__ msep, float* __restrict__ out) {
    int tid = threadIdx.x;
    float sx = 0.f, sh = 0.f, sm = 0.f;
    for (int i = tid; i < 4096; i += 256) {
        sx += rxe[i];
        sh += rhit[i];
    }
    for (int i = tid; i < 1024; i += 256) sm += msep[i];
#pragma unroll
    for (int off = 1; off < 64; off <<= 1) {
        sx += __shfl_xor(sx, off);
        sh += __shfl_xor(sh, off);
        sm += __shfl_xor(sm, off);
    }
    __shared__ float red[3][4];
    int w = tid >> 6;
    if ((tid & 63) == 0) {
        red[0][w] = sx;
        red[1][w] = sh;
        red[2][w] = sm;
    }
    __syncthreads();
    if (tid == 0) {
        sx = red[0][0] + red[0][1] + red[0][2] + red[0][3];
        sh = red[1][0] + red[1][1] + red[1][2] + red[1][3];
        sm = red[2][0] + red[2][1] + red[2][2] + red[2][3];
        float xe = sx * (1.f / 4096.f);
        float mse = sm / (12288.f * 1024.f);
        float accp = 100.f * sh * (1.f / 4096.f);
        out[0] = xe + mse;
        out[1] = xe;
        out[2] = mse;
        out[3] = accp;
    }
}

extern "C" void kernel_launch(void* const* d_in, const int* in_sizes, int n_in,
                              void* d_out, int out_size, void* d_ws, size_t ws_size,
                              hipStream_t stream) {
    const float* in_seq = (const float*)d_in[0];
    const float* out_seq = (const float*)d_in[1];
    const int* drop = (const int*)d_in[2];
    const int* keep = (const int*)d_in[3];
    float* out = (float*)d_out;

    char* w = (char*)d_ws;
    _Float16* Kf = (_Float16*)w; w += 33554432;  // 16384*1024*2
    _Float16* Pf = (_Float16*)w; w += 8388608;   // 4096*1024*2
    float* pmax = (float*)w; w += 4194304;       // 4096*256*4
    float* psum = (float*)w; w += 4194304;
    int* pidx = (int*)w; w += 4194304;
    float* xt = (float*)w; w += 16384;
    int* tgt = (int*)w; w += 16384;
    float* rxe = (float*)w; w += 16384;
    float* rhit = (float*)w; w += 16384;
    float* msep = (float*)w; w += 4096;

    // allow 144 KiB dynamic LDS (idempotent; not a stream op, capture-safe)
    (void)hipFuncSetAttribute((const void*)gemm_stats_k,
                              hipFuncAttributeMaxDynamicSharedMemorySize, 3 * LDSB * 2);

    conv_k<<<20480, 256, 0, stream>>>(in_seq, out_seq, drop, Kf, Pf, tgt);
    gemm_stats_k<<<2048, 512, 3 * LDSB * 2, stream>>>(Pf, Kf, tgt, pmax, psum, pidx, xt);
    pass2_k<<<4096, 64, 0, stream>>>(pmax, psum, pidx, xt, tgt, rxe, rhit);
    mse_partial_k<<<1024, 256, 0, stream>>>(in_seq, out_seq, keep, msep);
    finalize_k<<<1, 256, 0, stream>>>(rxe, rhit, msep, out);
}

// Round 5
// 354.552 us; speedup vs baseline: 1.6100x; 1.0691x over previous
//
#include <hip/hip_runtime.h>
#include <hip/hip_bf16.h>

// BERTCPCLoss: outputs (loss, xe, mse, acc). B=32, S=512, D=1024, DROPNUM=128
// lossmat = P @ K^T (4096 x 16384) fused with row max/argmax/sumexp/target-logit,
// softmax in exp2 domain (P pre-scaled by log2 e).
// GEMM: m201-style 256x256 8-phase template. BK=64, 8 waves (2Mx4N, 128x64/wave),
// LDS = 4 K-half slots x 32KB (A 256x32 + B 256x32) = 128 KiB ring.
// Phase = {ds_read frags + 2 global_load_lds -> barrier -> lgkmcnt(0) ->
//          setprio(1) 16 MFMA setprio(0) -> counted vmcnt(8) (odd phases) -> barrier}.
// Stage lookahead = 3 half-tiles; vmcnt never 0 until the tail (T4).
// K pre-swizzled in global: k ^= ((row>>1)&3)<<3, so global_load_lds is linear and
// swizzled ds_read_b128 is bank-uniform (rule #21: source-permute + read-permute).

typedef __attribute__((ext_vector_type(8))) _Float16 half8;
typedef __attribute__((ext_vector_type(4))) _Float16 half4v;
typedef __attribute__((ext_vector_type(4))) float f32x4;

#define MFMA16(a, b, c) __builtin_amdgcn_mfma_f32_16x16x32_f16((a), (b), (c), 0, 0, 0)

__device__ __forceinline__ float fexp2(float x) {
    float r;
    asm("v_exp_f32 %0, %1" : "=v"(r) : "v"(x));
    return r;
}
__device__ __forceinline__ float flog2(float x) {
    float r;
    asm("v_log_f32 %0, %1" : "=v"(r) : "v"(x));
    return r;
}

__device__ __forceinline__ void glds16(const _Float16* g, _Float16* l) {
    __builtin_amdgcn_global_load_lds(
        (const __attribute__((address_space(1))) unsigned int*)g,
        (__attribute__((address_space(3))) unsigned int*)l, 16, 0, 0);
}

// ---- conversion: f32 -> fp16, pre-swizzled k (XOR k bits 3..4 with (row>>1)&3) ----
// P additionally scaled by log2(e). blocks [0,16384): keys; [16384,20480): preds.
__global__ void conv_k(const float* __restrict__ in_seq, const float* __restrict__ out_seq,
                       const int* __restrict__ drop, _Float16* __restrict__ Kf,
                       _Float16* __restrict__ Pf, int* __restrict__ tgt) {
    const float C = 1.4426950408889634f;
    unsigned bid = blockIdx.x;
    if (bid < 16384u) {
        unsigned t = bid * 256u + threadIdx.x;
        unsigned idx = t * 4u;
        unsigned row = idx >> 10;
        unsigned k = idx & 1023u;
        float4 v = *(const float4*)(in_seq + idx);
        unsigned d = (row << 10) + (k ^ (((row >> 1) & 3u) << 3));
        half4v o = {(_Float16)v.x, (_Float16)v.y, (_Float16)v.z, (_Float16)v.w};
        *(half4v*)(Kf + d) = o;
    } else {
        unsigned t = (bid - 16384u) * 256u + threadIdx.x;
        unsigned idx = t * 4u;
        unsigned prow = idx >> 10;
        unsigned k = idx & 1023u;
        unsigned b = prow >> 7, j = prow & 127u;
        int srow = drop[b * 128u + j];
        size_t gsrc = ((size_t)((b << 9) + (unsigned)srow) << 10) + k;
        float4 v = *(const float4*)(out_seq + gsrc);
        unsigned d = (prow << 10) + (k ^ (((prow >> 1) & 3u) << 3));
        half4v o = {(_Float16)(v.x * C), (_Float16)(v.y * C), (_Float16)(v.z * C),
                    (_Float16)(v.w * C)};
        *(half4v*)(Pf + d) = o;
        if (k == 0) tgt[prow] = (int)((b << 9) + (unsigned)srow);
    }
}

// ---- fused GEMM + per-(row,chunk) softmax partials (exp2 domain) ----
// half-tile h = kt*2 + ks (h in [0,32)): slot h&3 holds A[256][k32] + B[256][k32].
// Reads of h at phases 2h (a mh0 + b) and 2h+1 (a mh1). Stage of h (4 glds: A-pair
// then B-pair) at phases 2h-6, 2h-5 (prologue for h<4). Wait vmcnt(8) end of odd
// phases (4 pairs in flight); tail 4/0.
__global__ __launch_bounds__(512, 2) void gemm_stats_k(
    const _Float16* __restrict__ Pf, const _Float16* __restrict__ Kf,
    const int* __restrict__ tgt,
    float* __restrict__ pmax, float* __restrict__ psum, int* __restrict__ pidx,
    float* __restrict__ xt) {
    extern __shared__ _Float16 lds[];  // 4 slots * 16384 elems = 128 KiB

    const int tid = threadIdx.x;  // 512
    const int lane = tid & 63;
    const int wave = tid >> 6;    // 0..7
    const int wm = wave >> 2, wn = wave & 3;
    const int lr = lane & 15, lk = lane >> 4;

    // XCD-aware swizzle: 1024 blocks, 8 XCDs -> 128 wg each; per-XCD bn-slab of 8.
    unsigned id = blockIdx.x;
    unsigned wg = (id & 7u) * 128u + (id >> 3);
    const int bn = wg >> 4, bm = wg & 15;  // bn 0..63, bm 0..15

    // staging: per glds, 512 threads x 16B = 128 rows x 32 halfwords
    const _Float16* aSrc = Pf + (size_t)(bm * 256 + (tid >> 2)) * 1024 + (tid & 3) * 8;
    const _Float16* bSrc = Kf + (size_t)(bn * 256 + (tid >> 2)) * 1024 + (tid & 3) * 8;

    // fragment-read swizzle (lane-constant): 16B slot XOR (row>>1)&3; rows = C16 + lr
    const unsigned swz = (unsigned)((lk ^ ((lr >> 1) & 3)) << 3);

    f32x4 acc[8][4] = {};
    half8 bfr[4];

    auto STAGEP = [&](int h, int ph) {  // ph 0 = A pair, 1 = B pair
        const int skt = h >> 1, sks = h & 1;
        const unsigned ss = (unsigned)(h & 3) * 16384u;
        const unsigned go = (unsigned)(skt * 64 + sks * 32);
        if (ph == 0) {
            glds16(aSrc + go, &lds[ss + tid * 8]);
            glds16(aSrc + 131072 + go, &lds[ss + 4096 + tid * 8]);
        } else {
            glds16(bSrc + go, &lds[ss + 8192 + tid * 8]);
            glds16(bSrc + 131072 + go, &lds[ss + 12288 + tid * 8]);
        }
    };

    // prologue: stage h0..h3 (16 glds); need h0 before phase 0
    #pragma unroll
    for (int h = 0; h < 4; ++h) {
        STAGEP(h, 0);
        STAGEP(h, 1);
    }
    asm volatile("s_waitcnt vmcnt(12)" ::: "memory");  // h0 resident
    __builtin_amdgcn_s_barrier();
    __builtin_amdgcn_sched_barrier(0);

    #pragma unroll
    for (int p = 0; p < 64; ++p) {
        const int q = p & 3;
        const int ks = q >> 1, mh = q & 1;
        const int kt = p >> 2;
        const unsigned sb = (unsigned)((2 * kt + ks) & 3) * 16384u;

        // ds-read fragments for this phase
        half8 a[4];
        #pragma unroll
        for (int i = 0; i < 4; ++i) {
            int r = wm * 128 + mh * 64 + i * 16 + lr;
            a[i] = *(const half8*)&lds[sb + r * 32 + swz];
        }
        if (q == 0 || q == 2) {
            #pragma unroll
            for (int n = 0; n < 4; ++n) {
                int r = wn * 64 + n * 16 + lr;
                bfr[n] = *(const half8*)&lds[sb + 8192 + r * 32 + swz];
            }
        }
        // stage pair p (phases 2..57): half-tile 4+(p-2)/2, A-pair then B-pair
        if (p >= 2 && p <= 57) STAGEP(4 + (p - 2) / 2, (p - 2) & 1);

        __builtin_amdgcn_s_barrier();
        asm volatile("s_waitcnt lgkmcnt(0)" ::: "memory");
        __builtin_amdgcn_sched_barrier(0);

        __builtin_amdgcn_s_setprio(1);
        #pragma unroll
        for (int i = 0; i < 4; ++i)
            #pragma unroll
            for (int n = 0; n < 4; ++n)
                acc[mh * 4 + i][n] = MFMA16(a[i], bfr[n], acc[mh * 4 + i][n]);
        __builtin_amdgcn_s_setprio(0);

        if (p & 1) {  // counted waits: next half-tile resident before its first read
            if (p < 59) {
                asm volatile("s_waitcnt vmcnt(8)" ::: "memory");
            } else if (p == 59) {
                asm volatile("s_waitcnt vmcnt(4)" ::: "memory");
            } else if (p == 61) {
                asm volatile("s_waitcnt vmcnt(0)" ::: "memory");
            }
        }
        if (p < 63) {
            __builtin_amdgcn_s_barrier();
            __builtin_amdgcn_sched_barrier(0);
        }
    }

    // epilogue: per-row 64-col chunk stats (exp2 domain)
    const int chunk = bn * 4 + wn;  // 0..255
    #pragma unroll
    for (int mi = 0; mi < 8; ++mi) {
        #pragma unroll
        for (int j = 0; j < 4; ++j) {
            int grow = bm * 256 + wm * 128 + mi * 16 + lk * 4 + j;
            int tcol = tgt[grow];
            float v0 = acc[mi][0][j], v1 = acc[mi][1][j], v2 = acc[mi][2][j],
                  v3 = acc[mi][3][j];
            int c0 = bn * 256 + wn * 64 + lr;
            if (c0 == tcol) xt[grow] = v0;
            if (c0 + 16 == tcol) xt[grow] = v1;
            if (c0 + 32 == tcol) xt[grow] = v2;
            if (c0 + 48 == tcol) xt[grow] = v3;
            float mx = fmaxf(fmaxf(v0, v1), fmaxf(v2, v3));
            #pragma unroll
            for (int off = 1; off < 16; off <<= 1) mx = fmaxf(mx, __shfl_xor(mx, off));
            int am = v0 == mx ? c0
                   : v1 == mx ? c0 + 16
                   : v2 == mx ? c0 + 32
                   : v3 == mx ? c0 + 48
                              : 0x7fffffff;
            #pragma unroll
            for (int off = 1; off < 16; off <<= 1) {
                int o = __shfl_xor(am, off);
                am = o < am ? o : am;
            }
            float s = fexp2(v0 - mx) + fexp2(v1 - mx) + fexp2(v2 - mx) + fexp2(v3 - mx);
            #pragma unroll
            for (int off = 1; off < 16; off <<= 1) s += __shfl_xor(s, off);
            if (lr == 0) {
                pmax[grow * 256 + chunk] = mx;
                psum[grow * 256 + chunk] = s;
                pidx[grow * 256 + chunk] = am;
            }
        }
    }
}

// ---- combine 256 chunks per row -> row xe / hit (exp2 domain) ----
__global__ void pass2_k(const float* __restrict__ pmax, const float* __restrict__ psum,
                        const int* __restrict__ pidx, const float* __restrict__ xt,
                        const int* __restrict__ tgt, float* __restrict__ rxe,
                        float* __restrict__ rhit) {
    int row = blockIdx.x;
    int t = threadIdx.x;  // 64
    float m = -3.0e38f, l = 0.f;
    int ai = 0x7fffffff;
    for (int c = t; c < 256; c += 64) {
        float cm = pmax[row * 256 + c];
        float cl = psum[row * 256 + c];
        int ci = pidx[row * 256 + c];
        if (cm > m || (cm == m && ci < ai)) {
            l = l * fexp2(m - cm) + cl;
            ai = ci;
            m = cm;
        } else {
            l += cl * fexp2(cm - m);
        }
    }
    #pragma unroll
    for (int off = 1; off < 64; off <<= 1) {
        float om = __shfl_xor(m, off);
        float ol = __shfl_xor(l, off);
        int oi = __shfl_xor(ai, off);
        if (om > m || (om == m && oi < ai)) {
            l = l * fexp2(m - om) + ol;
            ai = oi;
            m = om;
        } else {
            l += ol * fexp2(om - m);
        }
    }
    if (t == 0) {
        rxe[row] = (m + flog2(l) - xt[row]) * 0.69314718055994531f;
        rhit[row] = (ai == tgt[row]) ? 1.f : 0.f;
    }
}

// ---- MSE partials ----
__global__ void mse_partial_k(const float* __restrict__ inseq, const float* __restrict__ outseq,
                              const int* __restrict__ keep, float* __restrict__ msep) {
    float s = 0.f;
    for (unsigned f = blockIdx.x * 256u + threadIdx.x; f < 3145728u; f += 1024u * 256u) {
        unsigned rowid = f >> 8;
        unsigned kf = (f & 255u) << 2;
        unsigned b = rowid / 384u;
        unsigned j = rowid - b * 384u;
        int r = keep[b * 384u + j];
        size_t base = (((size_t)(b * 512u + (unsigned)r)) << 10) + kf;
        float4 a = *(const float4*)(inseq + base);
        float4 c = *(const float4*)(outseq + base);
        float dx = a.x - c.x, dy = a.y - c.y, dz = a.z - c.z, dw = a.w - c.w;
        s += dx * dx + dy * dy + dz * dz + dw * dw;
    }
    #pragma unroll
    for (int off = 1; off < 64; off <<= 1) s += __shfl_xor(s, off);
    __shared__ float red[4];
    if ((threadIdx.x & 63) == 0) red[threadIdx.x >> 6] = s;
    __syncthreads();
    if (threadIdx.x == 0) msep[blockIdx.x] = red[0] + red[1] + red[2] + red[3];
}

// ---- final reduce ----
__global__ void finalize_k(const float* __restrict__ rxe, const float* __restrict__ rhit,
                           const float* __restrict__ msep, float* __restrict__ out) {
    int tid = threadIdx.x;
    float sx = 0.f, sh = 0.f, sm = 0.f;
    for (int i = tid; i < 4096; i += 256) {
        sx += rxe[i];
        sh += rhit[i];
    }
    for (int i = tid; i < 1024; i += 256) sm += msep[i];
    #pragma unroll
    for (int off = 1; off < 64; off <<= 1) {
        sx += __shfl_xor(sx, off);
        sh += __shfl_xor(sh, off);
        sm += __shfl_xor(sm, off);
    }
    __shared__ float red[3][4];
    int w = tid >> 6;
    if ((tid & 63) == 0) {
        red[0][w] = sx;
        red[1][w] = sh;
        red[2][w] = sm;
    }
    __syncthreads();
    if (tid == 0) {
        sx = red[0][0] + red[0][1] + red[0][2] + red[0][3];
        sh = red[1][0] + red[1][1] + red[1][2] + red[1][3];
        sm = red[2][0] + red[2][1] + red[2][2] + red[2][3];
        float xe = sx * (1.f / 4096.f);
        float mse = sm / (12288.f * 1024.f);
        float accp = 100.f * sh * (1.f / 4096.f);
        out[0] = xe + mse;
        out[1] = xe;
        out[2] = mse;
        out[3] = accp;
    }
}

extern "C" void kernel_launch(void* const* d_in, const int* in_sizes, int n_in,
                              void* d_out, int out_size, void* d_ws, size_t ws_size,
                              hipStream_t stream) {
    const float* in_seq = (const float*)d_in[0];
    const float* out_seq = (const float*)d_in[1];
    const int* drop = (const int*)d_in[2];
    const int* keep = (const int*)d_in[3];
    float* out = (float*)d_out;

    char* w = (char*)d_ws;
    _Float16* Kf = (_Float16*)w; w += 33554432;  // 16384*1024*2
    _Float16* Pf = (_Float16*)w; w += 8388608;   // 4096*1024*2
    float* pmax = (float*)w; w += 4194304;       // 4096*256*4
    float* psum = (float*)w; w += 4194304;
    int* pidx = (int*)w; w += 4194304;
    float* xt = (float*)w; w += 16384;
    int* tgt = (int*)w; w += 16384;
    float* rxe = (float*)w; w += 16384;
    float* rhit = (float*)w; w += 16384;
    float* msep = (float*)w; w += 4096;

    static int attr_done = 0;
    if (!attr_done) {
        (void)hipFuncSetAttribute((const void*)gemm_stats_k,
                                  hipFuncAttributeMaxDynamicSharedMemorySize, 131072);
        attr_done = 1;
    }

    conv_k<<<20480, 256, 0, stream>>>(in_seq, out_seq, drop, Kf, Pf, tgt);
    gemm_stats_k<<<1024, 512, 131072, stream>>>(Pf, Kf, tgt, pmax, psum, pidx, xt);
    pass2_k<<<4096, 64, 0, stream>>>(pmax, psum, pidx, xt, tgt, rxe, rhit);
    mse_partial_k<<<1024, 256, 0, stream>>>(in_seq, out_seq, keep, msep);
    finalize_k<<<1, 256, 0, stream>>>(rxe, rhit, msep, out);
}

// Round 6
// 352.098 us; speedup vs baseline: 1.6212x; 1.0070x over previous
//
#include <hip/hip_runtime.h>
#include <hip/hip_bf16.h>

// BERTCPCLoss: outputs (loss, xe, mse, acc). B=32, S=512, D=1024, DROPNUM=128
// lossmat = P @ K^T (4096 x 16384) fused with row max/argmax/sumexp/target-logit,
// softmax in exp2 domain (P pre-scaled by log2 e).
// GEMM: 256x256 tile, BK=64, 8 waves (2Mx4N, 128x64/wave), 4-slot LDS ring
// (128 KiB). Round 6: fragment double-buffering — phase p issues ds_reads for
// phase p+1 (second reg buffer); MFMA(p) waits counted lgkmcnt (compiler-exact),
// so LDS drain overlaps the matrix pipe. vmcnt moved to even phases
// (8@p0, 6@p2..56, 4@58, 0@60); ONE barrier per phase.
// K pre-swizzled in global: k ^= ((row>>1)&3)<<3 (rule #21: src-permute+read-permute).

typedef __attribute__((ext_vector_type(8))) _Float16 half8;
typedef __attribute__((ext_vector_type(4))) _Float16 half4v;
typedef __attribute__((ext_vector_type(4))) float f32x4;

#define MFMA16(a, b, c) __builtin_amdgcn_mfma_f32_16x16x32_f16((a), (b), (c), 0, 0, 0)

__device__ __forceinline__ float fexp2(float x) {
    float r;
    asm("v_exp_f32 %0, %1" : "=v"(r) : "v"(x));
    return r;
}
__device__ __forceinline__ float flog2(float x) {
    float r;
    asm("v_log_f32 %0, %1" : "=v"(r) : "v"(x));
    return r;
}

__device__ __forceinline__ void glds16(const _Float16* g, _Float16* l) {
    __builtin_amdgcn_global_load_lds(
        (const __attribute__((address_space(1))) unsigned int*)g,
        (__attribute__((address_space(3))) unsigned int*)l, 16, 0, 0);
}

// ---- conversion: f32 -> fp16, pre-swizzled k (XOR k bits 3..4 with (row>>1)&3) ----
// P additionally scaled by log2(e). blocks [0,16384): keys; [16384,20480): preds.
__global__ void conv_k(const float* __restrict__ in_seq, const float* __restrict__ out_seq,
                       const int* __restrict__ drop, _Float16* __restrict__ Kf,
                       _Float16* __restrict__ Pf, int* __restrict__ tgt) {
    const float C = 1.4426950408889634f;
    unsigned bid = blockIdx.x;
    if (bid < 16384u) {
        unsigned t = bid * 256u + threadIdx.x;
        unsigned idx = t * 4u;
        unsigned row = idx >> 10;
        unsigned k = idx & 1023u;
        float4 v = *(const float4*)(in_seq + idx);
        unsigned d = (row << 10) + (k ^ (((row >> 1) & 3u) << 3));
        half4v o = {(_Float16)v.x, (_Float16)v.y, (_Float16)v.z, (_Float16)v.w};
        *(half4v*)(Kf + d) = o;
    } else {
        unsigned t = (bid - 16384u) * 256u + threadIdx.x;
        unsigned idx = t * 4u;
        unsigned prow = idx >> 10;
        unsigned k = idx & 1023u;
        unsigned b = prow >> 7, j = prow & 127u;
        int srow = drop[b * 128u + j];
        size_t gsrc = ((size_t)((b << 9) + (unsigned)srow) << 10) + k;
        float4 v = *(const float4*)(out_seq + gsrc);
        unsigned d = (prow << 10) + (k ^ (((prow >> 1) & 3u) << 3));
        half4v o = {(_Float16)(v.x * C), (_Float16)(v.y * C), (_Float16)(v.z * C),
                    (_Float16)(v.w * C)};
        *(half4v*)(Pf + d) = o;
        if (k == 0) tgt[prow] = (int)((b << 9) + (unsigned)srow);
    }
}

// ---- fused GEMM + per-(row,chunk) softmax partials (exp2 domain) ----
// half-tile h = p>>1 (phases 2h, 2h+1 share h). Slot h&3. Stage of h at phases
// 2h-6 (A-pair), 2h-5 (B-pair); prologue covers h0..h3. Frag reads for phase
// p+1 issue during phase p (a every phase, b at odd p). vmcnt at even phases.
__global__ __launch_bounds__(512, 2) void gemm_stats_k(
    const _Float16* __restrict__ Pf, const _Float16* __restrict__ Kf,
    const int* __restrict__ tgt,
    float* __restrict__ pmax, float* __restrict__ psum, int* __restrict__ pidx,
    float* __restrict__ xt) {
    extern __shared__ _Float16 lds[];  // 4 slots * 16384 elems = 128 KiB

    const int tid = threadIdx.x;  // 512
    const int lane = tid & 63;
    const int wave = tid >> 6;    // 0..7
    const int wm = wave >> 2, wn = wave & 3;
    const int lr = lane & 15, lk = lane >> 4;

    // XCD-aware swizzle: 1024 blocks, 8 XCDs -> 128 wg each; per-XCD bn-slab of 8.
    unsigned id = blockIdx.x;
    unsigned wg = (id & 7u) * 128u + (id >> 3);
    const int bn = wg >> 4, bm = wg & 15;  // bn 0..63, bm 0..15

    // staging: per glds, 512 threads x 16B = 128 rows x 32 halfwords
    const _Float16* aSrc = Pf + (size_t)(bm * 256 + (tid >> 2)) * 1024 + (tid & 3) * 8;
    const _Float16* bSrc = Kf + (size_t)(bn * 256 + (tid >> 2)) * 1024 + (tid & 3) * 8;

    // fragment-read swizzle (lane-constant): 16B slot XOR (row>>1)&3
    const unsigned swz = (unsigned)((lk ^ ((lr >> 1) & 3)) << 3);

    f32x4 acc[8][4] = {};
    half8 abuf[2][4], bbuf[2][4];

    auto STAGEP = [&](int h, int ph) {  // ph 0 = A pair, 1 = B pair
        const int skt = h >> 1, sks = h & 1;
        const unsigned ss = (unsigned)(h & 3) * 16384u;
        const unsigned go = (unsigned)(skt * 64 + sks * 32);
        if (ph == 0) {
            glds16(aSrc + go, &lds[ss + tid * 8]);
            glds16(aSrc + 131072 + go, &lds[ss + 4096 + tid * 8]);
        } else {
            glds16(bSrc + go, &lds[ss + 8192 + tid * 8]);
            glds16(bSrc + 131072 + go, &lds[ss + 12288 + tid * 8]);
        }
    };

    auto LOADA = [&](half8* dst, int p1) {  // a-frags for phase p1
        const int mh = p1 & 1;
        const unsigned sb = (unsigned)((p1 >> 1) & 3) * 16384u;
        #pragma unroll
        for (int i = 0; i < 4; ++i) {
            int r = wm * 128 + mh * 64 + i * 16 + lr;
            dst[i] = *(const half8*)&lds[sb + r * 32 + swz];
        }
    };
    auto LOADB = [&](half8* dst, int p1) {  // b-frags for phase p1 (even p1)
        const unsigned sb = (unsigned)((p1 >> 1) & 3) * 16384u;
        #pragma unroll
        for (int n = 0; n < 4; ++n) {
            int r = wn * 64 + n * 16 + lr;
            dst[n] = *(const half8*)&lds[sb + 8192 + r * 32 + swz];
        }
    };

    // prologue: stage h0..h3 (16 loads); publish h0; pre-read phase-0 frags
    #pragma unroll
    for (int h = 0; h < 4; ++h) {
        STAGEP(h, 0);
        STAGEP(h, 1);
    }
    asm volatile("s_waitcnt vmcnt(12)" ::: "memory");  // h0 resident (own loads)
    __builtin_amdgcn_s_barrier();                      // publish across waves
    __builtin_amdgcn_sched_barrier(0);
    LOADA(abuf[0], 0);
    LOADB(bbuf[0], 0);

    #pragma unroll
    for (int p = 0; p < 64; ++p) {
        // stage pair (phases 2..57): half-tile 4+(p-2)/2
        if (p >= 2 && p <= 57) STAGEP(4 + (p - 2) / 2, (p - 2) & 1);
        // issue frag reads for phase p+1 (overlap their drain with MFMA below)
        if (p < 63) LOADA(abuf[(p + 1) & 1], p + 1);
        if ((p & 1) && p < 63) LOADB(bbuf[((p + 1) >> 1) & 1], p + 1);
        __builtin_amdgcn_sched_barrier(0);  // pin read-issue before MFMA

        __builtin_amdgcn_s_setprio(1);
        #pragma unroll
        for (int i = 0; i < 4; ++i)
            #pragma unroll
            for (int n = 0; n < 4; ++n)
                acc[(p & 1) * 4 + i][n] = MFMA16(abuf[p & 1][i], bbuf[(p >> 1) & 1][n],
                                                 acc[(p & 1) * 4 + i][n]);
        __builtin_amdgcn_s_setprio(0);

        // counted vmcnt at even phases: half-tile (p+2)/2+... = h(p)/1+1 resident
        if (!(p & 1)) {
            if (p == 0) {
                asm volatile("s_waitcnt vmcnt(8)" ::: "memory");
            } else if (p <= 56) {
                asm volatile("s_waitcnt vmcnt(6)" ::: "memory");
            } else if (p == 58) {
                asm volatile("s_waitcnt vmcnt(4)" ::: "memory");
            } else if (p == 60) {
                asm volatile("s_waitcnt vmcnt(0)" ::: "memory");
            }
        }
        if (p < 63) {
            __builtin_amdgcn_s_barrier();
            __builtin_amdgcn_sched_barrier(0);
        }
    }

    // epilogue: per-row 64-col chunk stats (exp2 domain)
    const int chunk = bn * 4 + wn;  // 0..255
    #pragma unroll
    for (int mi = 0; mi < 8; ++mi) {
        #pragma unroll
        for (int j = 0; j < 4; ++j) {
            int grow = bm * 256 + wm * 128 + mi * 16 + lk * 4 + j;
            int tcol = tgt[grow];
            float v0 = acc[mi][0][j], v1 = acc[mi][1][j], v2 = acc[mi][2][j],
                  v3 = acc[mi][3][j];
            int c0 = bn * 256 + wn * 64 + lr;
            if (c0 == tcol) xt[grow] = v0;
            if (c0 + 16 == tcol) xt[grow] = v1;
            if (c0 + 32 == tcol) xt[grow] = v2;
            if (c0 + 48 == tcol) xt[grow] = v3;
            float mx = fmaxf(fmaxf(v0, v1), fmaxf(v2, v3));
            #pragma unroll
            for (int off = 1; off < 16; off <<= 1) mx = fmaxf(mx, __shfl_xor(mx, off));
            int am = v0 == mx ? c0
                   : v1 == mx ? c0 + 16
                   : v2 == mx ? c0 + 32
                   : v3 == mx ? c0 + 48
                              : 0x7fffffff;
            #pragma unroll
            for (int off = 1; off < 16; off <<= 1) {
                int o = __shfl_xor(am, off);
                am = o < am ? o : am;
            }
            float s = fexp2(v0 - mx) + fexp2(v1 - mx) + fexp2(v2 - mx) + fexp2(v3 - mx);
            #pragma unroll
            for (int off = 1; off < 16; off <<= 1) s += __shfl_xor(s, off);
            if (lr == 0) {
                pmax[grow * 256 + chunk] = mx;
                psum[grow * 256 + chunk] = s;
                pidx[grow * 256 + chunk] = am;
            }
        }
    }
}

// ---- combine 256 chunks per row -> row xe / hit (exp2 domain) ----
__global__ void pass2_k(const float* __restrict__ pmax, const float* __restrict__ psum,
                        const int* __restrict__ pidx, const float* __restrict__ xt,
                        const int* __restrict__ tgt, float* __restrict__ rxe,
                        float* __restrict__ rhit) {
    int row = blockIdx.x;
    int t = threadIdx.x;  // 64
    float m = -3.0e38f, l = 0.f;
    int ai = 0x7fffffff;
    for (int c = t; c < 256; c += 64) {
        float cm = pmax[row * 256 + c];
        float cl = psum[row * 256 + c];
        int ci = pidx[row * 256 + c];
        if (cm > m || (cm == m && ci < ai)) {
            l = l * fexp2(m - cm) + cl;
            ai = ci;
            m = cm;
        } else {
            l += cl * fexp2(cm - m);
        }
    }
    #pragma unroll
    for (int off = 1; off < 64; off <<= 1) {
        float om = __shfl_xor(m, off);
        float ol = __shfl_xor(l, off);
        int oi = __shfl_xor(ai, off);
        if (om > m || (om == m && oi < ai)) {
            l = l * fexp2(m - om) + ol;
            ai = oi;
            m = om;
        } else {
            l += ol * fexp2(om - m);
        }
    }
    if (t == 0) {
        rxe[row] = (m + flog2(l) - xt[row]) * 0.69314718055994531f;
        rhit[row] = (ai == tgt[row]) ? 1.f : 0.f;
    }
}

// ---- MSE partials ----
__global__ void mse_partial_k(const float* __restrict__ inseq, const float* __restrict__ outseq,
                              const int* __restrict__ keep, float* __restrict__ msep) {
    float s = 0.f;
    for (unsigned f = blockIdx.x * 256u + threadIdx.x; f < 3145728u; f += 1024u * 256u) {
        unsigned rowid = f >> 8;
        unsigned kf = (f & 255u) << 2;
        unsigned b = rowid / 384u;
        unsigned j = rowid - b * 384u;
        int r = keep[b * 384u + j];
        size_t base = (((size_t)(b * 512u + (unsigned)r)) << 10) + kf;
        float4 a = *(const float4*)(inseq + base);
        float4 c = *(const float4*)(outseq + base);
        float dx = a.x - c.x, dy = a.y - c.y, dz = a.z - c.z, dw = a.w - c.w;
        s += dx * dx + dy * dy + dz * dz + dw * dw;
    }
    #pragma unroll
    for (int off = 1; off < 64; off <<= 1) s += __shfl_xor(s, off);
    __shared__ float red[4];
    if ((threadIdx.x & 63) == 0) red[threadIdx.x >> 6] = s;
    __syncthreads();
    if (threadIdx.x == 0) msep[blockIdx.x] = red[0] + red[1] + red[2] + red[3];
}

// ---- final reduce ----
__global__ void finalize_k(const float* __restrict__ rxe, const float* __restrict__ rhit,
                           const float* __restrict__ msep, float* __restrict__ out) {
    int tid = threadIdx.x;
    float sx = 0.f, sh = 0.f, sm = 0.f;
    for (int i = tid; i < 4096; i += 256) {
        sx += rxe[i];
        sh += rhit[i];
    }
    for (int i = tid; i < 1024; i += 256) sm += msep[i];
    #pragma unroll
    for (int off = 1; off < 64; off <<= 1) {
        sx += __shfl_xor(sx, off);
        sh += __shfl_xor(sh, off);
        sm += __shfl_xor(sm, off);
    }
    __shared__ float red[3][4];
    int w = tid >> 6;
    if ((tid & 63) == 0) {
        red[0][w] = sx;
        red[1][w] = sh;
        red[2][w] = sm;
    }
    __syncthreads();
    if (tid == 0) {
        sx = red[0][0] + red[0][1] + red[0][2] + red[0][3];
        sh = red[1][0] + red[1][1] + red[1][2] + red[1][3];
        sm = red[2][0] + red[2][1] + red[2][2] + red[2][3];
        float xe = sx * (1.f / 4096.f);
        float mse = sm / (12288.f * 1024.f);
        float accp = 100.f * sh * (1.f / 4096.f);
        out[0] = xe + mse;
        out[1] = xe;
        out[2] = mse;
        out[3] = accp;
    }
}

extern "C" void kernel_launch(void* const* d_in, const int* in_sizes, int n_in,
                              void* d_out, int out_size, void* d_ws, size_t ws_size,
                              hipStream_t stream) {
    const float* in_seq = (const float*)d_in[0];
    const float* out_seq = (const float*)d_in[1];
    const int* drop = (const int*)d_in[2];
    const int* keep = (const int*)d_in[3];
    float* out = (float*)d_out;

    char* w = (char*)d_ws;
    _Float16* Kf = (_Float16*)w; w += 33554432;  // 16384*1024*2
    _Float16* Pf = (_Float16*)w; w += 8388608;   // 4096*1024*2
    float* pmax = (float*)w; w += 4194304;       // 4096*256*4
    float* psum = (float*)w; w += 4194304;
    int* pidx = (int*)w; w += 4194304;
    float* xt = (float*)w; w += 16384;
    int* tgt = (int*)w; w += 16384;
    float* rxe = (float*)w; w += 16384;
    float* rhit = (float*)w; w += 16384;
    float* msep = (float*)w; w += 4096;

    static int attr_done = 0;
    if (!attr_done) {
        (void)hipFuncSetAttribute((const void*)gemm_stats_k,
                                  hipFuncAttributeMaxDynamicSharedMemorySize, 131072);
        attr_done = 1;
    }

    conv_k<<<20480, 256, 0, stream>>>(in_seq, out_seq, drop, Kf, Pf, tgt);
    gemm_stats_k<<<1024, 512, 131072, stream>>>(Pf, Kf, tgt, pmax, psum, pidx, xt);
    pass2_k<<<4096, 64, 0, stream>>>(pmax, psum, pidx, xt, tgt, rxe, rhit);
    mse_partial_k<<<1024, 256, 0, stream>>>(in_seq, out_seq, keep, msep);
    finalize_k<<<1, 256, 0, stream>>>(rxe, rhit, msep, out);
}